// Round 8
// baseline (12211.327 us; speedup 1.0000x reference)
//
#include <hip/hip_runtime.h>
#include <math.h>

#define Bb 128
#define Tt 1024
#define Ff 128
#define Hh 256
#define Oo 128

// ---- d_ws layout (u32 words) ----
#define P_WHH  0u          // 8 roles * 12288 (96 rows x 32 uint4-slots, swizzled)
#define P_WIH  98304u      // 8 roles * 6144  (96 rows x 16 slots, swizzled)
#define P_WSW  147456u     // 8 roles * 4096  (sel 128x16 + out 128x16 u32)
#define P_FLAG 180224u     // 256 flags
#define P_HX   180480u     // 2 * 256 * 1088 mailboxes
#define HXS    1088u
#define P_PART 737536u     // 32 partials
#define PACK_TOTAL 180224u

// ---- LDS layout (u32) ----
#define WHHo 0
#define WIHo 12288
#define H2o  18432
#define WXo  18944
#define GTo  19200
#define LDSU 19584        // 78336 bytes -> 2 blocks/CU capacity

typedef _Float16 half2_t __attribute__((ext_vector_type(2)));
union U32H2 { unsigned u; half2_t h; };
union U32F  { unsigned u; float f; };

__device__ __forceinline__ float dot2f(unsigned wu, unsigned hu, float acc) {
    U32H2 a, b; a.u = wu; b.u = hu;
#if __has_builtin(__builtin_amdgcn_fdot2)
    return __builtin_amdgcn_fdot2(a.h, b.h, acc, false);
#else
    return acc + (float)a.h.x * (float)b.h.x + (float)a.h.y * (float)b.h.y;
#endif
}
__device__ __forceinline__ float dotu4(uint4 w, uint4 h, float a) {
    a = dot2f(w.x, h.x, a); a = dot2f(w.y, h.y, a);
    a = dot2f(w.z, h.z, a); a = dot2f(w.w, h.w, a);
    return a;
}

// Pack weights to fp16 pairs in the exact consumer layout (see R7 notes).
__global__ void pack_kernel(const float* __restrict__ wih, const float* __restrict__ whh,
                            const float* __restrict__ wsel, const float* __restrict__ wout,
                            unsigned* __restrict__ dst) {
    unsigned pid = blockIdx.x * 256 + threadIdx.x;
    if (pid >= PACK_TOTAL) return;
    float v0, v1;
    if (pid < P_WIH) {
        unsigned role = pid / 12288u, rem = pid % 12288u;
        unsigned q4 = rem >> 2, i = rem & 3u;
        unsigned r = q4 >> 5, s = q4 & 31u;
        unsigned g = (s & ~7u) | ((s & 7u) ^ (r & 7u));
        unsigned R = (r >> 5) * 256u + role * 32u + (r & 31u);
        unsigned kd = g * 8u + i * 2u;
        v0 = whh[R * 256u + kd]; v1 = whh[R * 256u + kd + 1u];
    } else if (pid < P_WSW) {
        unsigned p2 = pid - P_WIH;
        unsigned role = p2 / 6144u, rem = p2 % 6144u;
        unsigned q4 = rem >> 2, i = rem & 3u;
        unsigned r = q4 >> 4, s = q4 & 15u;
        unsigned g = (s & 8u) | ((s & 7u) ^ (r & 7u));
        unsigned R = (r >> 5) * 256u + role * 32u + (r & 31u);
        unsigned kd = g * 8u + i * 2u;
        v0 = wih[R * 128u + kd]; v1 = wih[R * 128u + kd + 1u];
    } else {
        unsigned p3 = pid - P_WSW;
        unsigned role = p3 >> 12, r4 = p3 & 4095u;
        unsigned which = r4 >> 11, row = (r4 >> 4) & 127u, m = r4 & 15u;
        unsigned kd = role * 32u + m * 2u;
        const float* src = which ? wout : wsel;
        v0 = src[row * 256u + kd]; v1 = src[row * 256u + kd + 1u];
    }
    U32H2 u; u.h = (half2_t){ (_Float16)v0, (_Float16)v1 };
    dst[pid] = u.u;
}

__global__ void zero_flags(unsigned* __restrict__ flags) { flags[threadIdx.x] = 0u; }

__global__ __launch_bounds__(512)
void gru_kernel(const float* __restrict__ x, const float* __restrict__ noise,
                const float* __restrict__ bih, const float* __restrict__ bhh,
                const float* __restrict__ bout, const float* __restrict__ bsel,
                unsigned* __restrict__ wsu,
                float* __restrict__ outputs, float* __restrict__ selw,
                float* __restrict__ partials) {
    extern __shared__ unsigned L[];
    float* gatesf = (float*)(L + GTo);    // [4 brow][4 gate'][32]

    const int bid = blockIdx.x;
    const int role = bid >> 5;            // hidden slice 0..7 (32 dims)
    const int group = bid & 31;           // 4 batch rows
    const int tid = threadIdx.x;

    // ---- stage weights: big mats -> LDS (immune to per-step L2 invalidation) ----
    for (int i = tid; i < 12288; i += 512) L[WHHo + i] = wsu[P_WHH + (unsigned)role * 12288u + i];
    for (int i = tid; i < 6144;  i += 512) L[WIHo + i] = wsu[P_WIH + (unsigned)role * 6144u + i];

    const int bb = tid >> 7, fr = tid & 127;      // C/E task keys
    const int grow = group * 4 + bb;

    // sel/out k-slices -> registers (32 u32/thread)
    unsigned wsl[16], wot[16];
    #pragma unroll
    for (int m = 0; m < 16; m++) wsl[m] = wsu[P_WSW + (unsigned)role * 4096u + (unsigned)fr * 16u + m];
    #pragma unroll
    for (int m = 0; m < 16; m++) wot[m] = wsu[P_WSW + (unsigned)role * 4096u + 2048u + (unsigned)fr * 16u + m];

    // ---- A-phase keys & biases ----
    const int r = tid >> 2, ks = tid & 3;         // row in [0,96), k-quarter
    const bool r96 = (r < 96);
    const int rx = r & 7;
    float biasA = 0.f, biasB = 0.f;
    if (r96) {
        int R = (r >> 5) * 256 + role * 32 + (r & 31);
        if (r < 64) biasA = bih[R] + bhh[R];
        else { biasA = bih[R]; biasB = bhh[R]; }
    }
    const float bsel_f = bsel[fr];
    const float bout_f = bout[fr];

    // ---- init: h=0, wx = x[:,0,:], selw[0]=1 ----
    L[H2o + tid] = 0u;                   // full 4x256 h zeroed (512 u32)
    {
        float x0 = x[((size_t)grow * Tt) * Ff + fr];
        float xp = __shfl_xor(x0, 1, 64);
        if (!(fr & 1)) {
            U32H2 v; v.h = (half2_t){ (_Float16)x0, (_Float16)xp };
            L[WXo + bb * 64 + (fr >> 1)] = v.u;
        }
        if (role == 0) selw[(size_t)grow * Ff + fr] = 1.0f;
    }
    __syncthreads();

    unsigned* flags = wsu + P_FLAG;
    unsigned* hx    = wsu + P_HX;

    const uint4* whh4 = (const uint4*)(L + WHHo);
    const uint4* wih4 = (const uint4*)(L + WIHo);
    const uint4* h4   = (const uint4*)(L + H2o);
    const uint4* wx4  = (const uint4*)(L + WXo);

    const int bbH = tid >> 5, dimH = tid & 31;    // H task keys (tid<128)
    float h_old = 0.f, ssum = 0.f;

    for (int t = 0; t < Tt; ++t) {
        const unsigned mbMy = ((unsigned)(t & 1) * 256u + (unsigned)bid) * HXS;

        // prefetch next-step inputs (consumed in E)
        float xv = 0.f, nzv = 0.f;
        if (t < Tt - 1) {
            xv  = x[((size_t)grow * Tt + (t + 1)) * Ff + fr];
            nzv = noise[((size_t)t * Bb + grow) * Ff + fr];
        }

        // ---- A: gate rows (96) x k-quarter (4), all 4 brows per thread ----
        float aH0=0.f,aH1=0.f,aH2=0.f,aH3=0.f,aI0=0.f,aI1=0.f,aI2=0.f,aI3=0.f;
        if (r96) {
            #pragma unroll
            for (int j = 0; j < 8; ++j) {
                uint4 wv = whh4[r * 32 + ks * 8 + (j ^ rx)];
                aH0 = dotu4(wv, h4[      ks * 8 + j], aH0);
                aH1 = dotu4(wv, h4[32  + ks * 8 + j], aH1);
                aH2 = dotu4(wv, h4[64  + ks * 8 + j], aH2);
                aH3 = dotu4(wv, h4[96  + ks * 8 + j], aH3);
            }
            #pragma unroll
            for (int j = 0; j < 4; ++j) {
                int g = ks * 4 + j;
                uint4 wv = wih4[r * 16 + ((g & 8) | ((g & 7) ^ rx))];
                aI0 = dotu4(wv, wx4[     g], aI0);
                aI1 = dotu4(wv, wx4[16 + g], aI1);
                aI2 = dotu4(wv, wx4[32 + g], aI2);
                aI3 = dotu4(wv, wx4[48 + g], aI3);
            }
        }
        // ks-reduction (lanes differ in low 2 bits)
        aH0 += __shfl_xor(aH0,1,64); aH0 += __shfl_xor(aH0,2,64);
        aH1 += __shfl_xor(aH1,1,64); aH1 += __shfl_xor(aH1,2,64);
        aH2 += __shfl_xor(aH2,1,64); aH2 += __shfl_xor(aH2,2,64);
        aH3 += __shfl_xor(aH3,1,64); aH3 += __shfl_xor(aH3,2,64);
        aI0 += __shfl_xor(aI0,1,64); aI0 += __shfl_xor(aI0,2,64);
        aI1 += __shfl_xor(aI1,1,64); aI1 += __shfl_xor(aI1,2,64);
        aI2 += __shfl_xor(aI2,1,64); aI2 += __shfl_xor(aI2,2,64);
        aI3 += __shfl_xor(aI3,1,64); aI3 += __shfl_xor(aI3,2,64);
        if (r96 && ks == 0) {
            int dim = r & 31;
            if (r < 64) {
                int gate = r >> 5;
                gatesf[      gate * 32 + dim] = aH0 + aI0 + biasA;
                gatesf[128 + gate * 32 + dim] = aH1 + aI1 + biasA;
                gatesf[256 + gate * 32 + dim] = aH2 + aI2 + biasA;
                gatesf[384 + gate * 32 + dim] = aH3 + aI3 + biasA;
            } else {
                gatesf[       64 + dim] = aI0 + biasA;  gatesf[       96 + dim] = aH0 + biasB;
                gatesf[128 +  64 + dim] = aI1 + biasA;  gatesf[128 +  96 + dim] = aH1 + biasB;
                gatesf[256 +  64 + dim] = aI2 + biasA;  gatesf[256 +  96 + dim] = aH2 + biasB;
                gatesf[384 +  64 + dim] = aI3 + biasA;  gatesf[384 +  96 + dim] = aH3 + biasB;
            }
        }
        __syncthreads();                               // B1

        // ---- H: finalize own 32-dim slice for own 4 brows (tid<128) ----
        if (tid < 128) {
            float g0 = gatesf[bbH * 128 +       dimH];
            float g1 = gatesf[bbH * 128 + 32  + dimH];
            float g2 = gatesf[bbH * 128 + 64  + dimH];
            float g3 = gatesf[bbH * 128 + 96  + dimH];
            float rg = 1.f / (1.f + expf(-g0));
            float zg = 1.f / (1.f + expf(-g1));
            float ng = tanhf(g2 + rg * g3);
            float h  = (1.f - zg) * ng + zg * h_old;
            h_old = h;
            float hp = __shfl_xor(h, 1, 64);
            if (!(dimH & 1)) {
                U32H2 v; v.h = (half2_t){ (_Float16)h, (_Float16)hp };
                L[H2o + bbH * 128 + role * 16 + (dimH >> 1)] = v.u;
                __hip_atomic_store(&hx[mbMy + bbH * 16u + (dimH >> 1)], v.u,
                                   __ATOMIC_RELAXED, __HIP_MEMORY_SCOPE_AGENT);
            }
        }
        __syncthreads();                               // B2 (own h slice in LDS)

        // ---- C: sel/out k-partials over own 32 dims (weights in regs) ----
        float p_sel = 0.f, p_out = 0.f;
        #pragma unroll
        for (int mm = 0; mm < 4; ++mm) {
            uint4 hv = h4[bb * 32 + role * 4 + mm];
            p_sel = dot2f(wsl[mm*4+0], hv.x, p_sel); p_sel = dot2f(wsl[mm*4+1], hv.y, p_sel);
            p_sel = dot2f(wsl[mm*4+2], hv.z, p_sel); p_sel = dot2f(wsl[mm*4+3], hv.w, p_sel);
            p_out = dot2f(wot[mm*4+0], hv.x, p_out); p_out = dot2f(wot[mm*4+1], hv.y, p_out);
            p_out = dot2f(wot[mm*4+2], hv.z, p_out); p_out = dot2f(wot[mm*4+3], hv.w, p_out);
        }
        {
            U32F u; u.f = p_sel;
            __hip_atomic_store(&hx[mbMy + 64u + (unsigned)bb * 256u + (unsigned)fr], u.u,
                               __ATOMIC_RELAXED, __HIP_MEMORY_SCOPE_AGENT);
            U32F v; v.f = p_out;
            __hip_atomic_store(&hx[mbMy + 64u + (unsigned)bb * 256u + 128u + (unsigned)fr], v.u,
                               __ATOMIC_RELAXED, __HIP_MEMORY_SCOPE_AGENT);
        }
        __syncthreads();                               // B3 (compiler drains vmcnt(0) before barrier)

        // ---- flag protocol: store FIRST (all blocks), barrier, THEN spin ----
        // R6/R7 deadlock root-cause: store & spin were divergent branches of one
        // wave; exec-mask serialization order is compiler-chosen, so the spin
        // could run before the store on every block -> global deadlock.
        if (tid == 0)
            __hip_atomic_store(&flags[bid], (unsigned)(t + 1),
                               __ATOMIC_RELEASE, __HIP_MEMORY_SCOPE_AGENT);
        __syncthreads();                               // B4a: flag store completed & visible
        if (tid < 7) {
            int prole = (role + 1 + tid) & 7;          // one partner per thread
            unsigned* pf = &flags[(prole << 5) | group];
            while (__hip_atomic_load(pf, __ATOMIC_RELAXED, __HIP_MEMORY_SCOPE_AGENT) < (unsigned)(t + 1))
                __builtin_amdgcn_s_sleep(2);
            (void)__hip_atomic_load(pf, __ATOMIC_ACQUIRE, __HIP_MEMORY_SCOPE_AGENT);
        }
        __syncthreads();                               // B4b

        // ---- E: assemble partner h slices + merge partials; outputs, w, wx ----
        if (tid < 448) {
            int pn = tid >> 6, s = tid & 63;
            int prole = (role + 1 + pn) & 7;
            unsigned mbP = ((unsigned)(t & 1) * 256u + (unsigned)((prole << 5) | group)) * HXS;
            unsigned v = __hip_atomic_load(&hx[mbP + (unsigned)s],
                                           __ATOMIC_RELAXED, __HIP_MEMORY_SCOPE_AGENT);
            L[H2o + (s >> 4) * 128 + prole * 16 + (s & 15)] = v;
        }
        float ptot = p_sel + bsel_f;
        float otot = p_out + bout_f;
        const bool own_out = ((fr >> 4) == role);
        #pragma unroll
        for (int pn = 0; pn < 7; ++pn) {
            int prole = (role + 1 + pn) & 7;
            unsigned mbP = ((unsigned)(t & 1) * 256u + (unsigned)((prole << 5) | group)) * HXS;
            U32F u; u.u = __hip_atomic_load(&hx[mbP + 64u + (unsigned)bb * 256u + (unsigned)fr],
                                            __ATOMIC_RELAXED, __HIP_MEMORY_SCOPE_AGENT);
            ptot += u.f;
            if (own_out) {
                U32F v; v.u = __hip_atomic_load(&hx[mbP + 64u + (unsigned)bb * 256u + 128u + (unsigned)fr],
                                                __ATOMIC_RELAXED, __HIP_MEMORY_SCOPE_AGENT);
                otot += v.f;
            }
        }
        if (own_out)
            outputs[((size_t)t * Bb + grow) * Oo + fr] = otot;
        if (t < Tt - 1) {
            float arg = (ptot + logf(nzv + 1e-20f) - logf(1.f - nzv + 1e-20f)) * 20.0f;
            float w = 1.f / (1.f + expf(-arg));
            if (role == 0) {
                selw[((size_t)(t + 1) * Bb + grow) * Ff + fr] = w;
                ssum += w;
            }
            float wxv = w * xv;
            float wp = __shfl_xor(wxv, 1, 64);
            if (!(fr & 1)) {
                U32H2 v; v.h = (half2_t){ (_Float16)wxv, (_Float16)wp };
                L[WXo + bb * 64 + (fr >> 1)] = v.u;
            }
        }
        __syncthreads();                               // B5 (h/wx ready for next A)
    }

    // ---- selection-sum partial (role-0 blocks) ----
    float* red = (float*)L;                            // reuse weight LDS post-loop
    red[tid] = ssum;
    __syncthreads();
    for (int s = 256; s > 0; s >>= 1) {
        if (tid < s) red[tid] += red[tid + s];
        __syncthreads();
    }
    if (tid == 0 && role == 0) partials[group] = red[0];
}

__global__ void finalize_kernel(const float* __restrict__ partials, float* __restrict__ out_scalar) {
    __shared__ float red[32];
    int t = threadIdx.x;
    red[t] = partials[t];
    __syncthreads();
    for (int s = 16; s > 0; s >>= 1) {
        if (t < s) red[t] += red[t + s];
        __syncthreads();
    }
    if (t == 0) out_scalar[0] = red[0];
}

extern "C" void kernel_launch(void* const* d_in, const int* in_sizes, int n_in,
                              void* d_out, int out_size, void* d_ws, size_t ws_size,
                              hipStream_t stream) {
    const float* x     = (const float*)d_in[0];
    const float* noise = (const float*)d_in[1];
    const float* w_ih  = (const float*)d_in[2];
    const float* w_hh  = (const float*)d_in[3];
    const float* b_ih  = (const float*)d_in[4];
    const float* b_hh  = (const float*)d_in[5];
    const float* W_out = (const float*)d_in[6];
    const float* b_out = (const float*)d_in[7];
    const float* W_sel = (const float*)d_in[8];
    const float* b_sel = (const float*)d_in[9];

    unsigned* wsu = (unsigned*)d_ws;
    float* out = (float*)d_out;
    float* outputs = out;                               // [T,B,O]
    float* nsel    = out + (size_t)Tt * Bb * Oo;        // scalar
    float* selw    = nsel + 1;                          // [T,B,F]
    float* partials = (float*)(wsu + P_PART);

    // allow >64KB dynamic LDS (78336 B)
    (void)hipFuncSetAttribute((const void*)gru_kernel,
                              hipFuncAttributeMaxDynamicSharedMemorySize, LDSU * 4);

    pack_kernel<<<(PACK_TOTAL + 255) / 256, 256, 0, stream>>>(w_ih, w_hh, W_sel, W_out, wsu);
    zero_flags<<<1, 256, 0, stream>>>(wsu + P_FLAG);
    gru_kernel<<<256, 512, LDSU * 4, stream>>>(x, noise, b_ih, b_hh, b_out, b_sel,
                                               wsu, outputs, selw, partials);
    finalize_kernel<<<1, 32, 0, stream>>>(partials, nsel);
}

// Round 9
// 4403.824 us; speedup vs baseline: 2.7729x; 2.7729x over previous
//
#include <hip/hip_runtime.h>
#include <math.h>

#define Bb 128
#define Tt 1024
#define Ff 128
#define Hh 256
#define Oo 128

#define NW 192u  // resident weight u32s per thread

// d_ws layout (u32 words)
#define P_PACK 0u
#define PACK_SZ  (2u * NW * 512u)          // 196608
#define P_FLAG (P_PACK + PACK_SZ)          // 256 flags
#define P_HX   (P_FLAG + 256u)             // 2 bufs * 256 * 64 u32
#define HXS    64u
#define P_PART (P_HX + 2u * 256u * HXS)

typedef _Float16 half2_t __attribute__((ext_vector_type(2)));
union U32H2 { unsigned u; half2_t h; };

__device__ __forceinline__ float dot2f(unsigned wu, unsigned hu, float acc) {
    U32H2 a, b; a.u = wu; b.u = hu;
#if __has_builtin(__builtin_amdgcn_fdot2)
    return __builtin_amdgcn_fdot2(a.h, b.h, acc, false);
#else
    return acc + (float)a.h.x * (float)b.h.x + (float)a.h.y * (float)b.h.y;
#endif
}

// R4-validated pack: dst[(role*NW + j)*512 + tid]
// j in [0,96)   : whh gate g=j>>5, p=j&31      -> row g*256+role*128+d, k-u32 32q+p
// j in [96,144) : wih gate g=(j-96)>>4, p&15   -> row g*256+role*128+d, k-u32 16q+p
// j in [144,160): wsel OWN-half  row d, k-u32 role*64 + q*16 + (j-144)
// j in [160,176): wsel PART-half row d, k-u32 (1-role)*64 + q*16 + (j-160)
// j in [176,192): wout row role*64+orow, k-u32 oct*16 + (j-176)
__global__ void pack_kernel(const float* __restrict__ wih, const float* __restrict__ whh,
                            const float* __restrict__ wsel, const float* __restrict__ wout,
                            unsigned* __restrict__ dst) {
    unsigned pid = blockIdx.x * 256 + threadIdx.x;
    if (pid >= 2u * NW * 512u) return;
    int tid = pid & 511;
    int j = (pid >> 9) % NW;
    int role = pid / (NW * 512u);
    int d = tid & 127, q = tid >> 7;
    int orow = tid & 63, oct = tid >> 6;
    const float* src; int idx0;
    if (j < 96) {
        int g = j >> 5, p = j & 31;
        int R = g * 256 + role * 128 + d;
        src = whh; idx0 = R * 256 + 2 * (32 * q + p);
    } else if (j < 144) {
        int jj = j - 96, g = jj >> 4, p = jj & 15;
        int R = g * 256 + role * 128 + d;
        src = wih; idx0 = R * 128 + 2 * (16 * q + p);
    } else if (j < 160) {
        int jj = j - 144;
        src = wsel; idx0 = d * 256 + 2 * (role * 64 + q * 16 + jj);
    } else if (j < 176) {
        int jj = j - 160;
        src = wsel; idx0 = d * 256 + 2 * ((1 - role) * 64 + q * 16 + jj);
    } else {
        int jj = j - 176;
        int R = role * 64 + orow;
        src = wout; idx0 = R * 256 + 2 * (oct * 16 + jj);
    }
    U32H2 v; v.h = (half2_t){ (_Float16)src[idx0], (_Float16)src[idx0 + 1] };
    dst[pid] = v.u;
}

__global__ void zero_flags(unsigned* __restrict__ flags) { flags[threadIdx.x] = 0u; }

__global__ __launch_bounds__(512)
void gru_kernel(const float* __restrict__ x, const float* __restrict__ noise,
                const float* __restrict__ bih, const float* __restrict__ bhh,
                const float* __restrict__ bout, const float* __restrict__ bsel,
                unsigned* __restrict__ wsu,
                float* __restrict__ outputs, float* __restrict__ selw,
                float* __restrict__ partials) {
    const int bid = blockIdx.x;
    const int row = bid & 127;
    const int role = bid >> 7;            // pair (row, row+128): same XCD mod-8 (perf only)
    const int tid = threadIdx.x;
    const int d = tid & 127, q = tid >> 7;
    const int orow = tid & 63, oct = tid >> 6;

    __shared__ unsigned h2u[128];         // full h as fp16 pairs
    __shared__ unsigned wxu[64];          // gated input as fp16 pairs
    __shared__ float red[512 * 5];        // stride-5 padded partials

    // ---- resident weights (R4 layout) ----
    unsigned whh2[96], wih2[48], wselo[16], wselp[16], wout2[16];
    const unsigned base = (unsigned)(role * NW) * 512u + (unsigned)tid;
    const unsigned* __restrict__ pk = wsu + P_PACK;
    #pragma unroll
    for (int j = 0; j < 96; j++) whh2[j] = pk[base + j * 512];
    #pragma unroll
    for (int j = 0; j < 48; j++) wih2[j] = pk[base + (96 + j) * 512];
    #pragma unroll
    for (int j = 0; j < 16; j++) wselo[j] = pk[base + (144 + j) * 512];
    #pragma unroll
    for (int j = 0; j < 16; j++) wselp[j] = pk[base + (160 + j) * 512];
    #pragma unroll
    for (int j = 0; j < 16; j++) wout2[j] = pk[base + (176 + j) * 512];
    #pragma unroll
    for (int j = 0; j < 96; j++) asm volatile("" : "+v"(whh2[j]));
    #pragma unroll
    for (int j = 0; j < 48; j++) asm volatile("" : "+v"(wih2[j]));
    #pragma unroll
    for (int j = 0; j < 16; j++) asm volatile("" : "+v"(wselo[j]));
    #pragma unroll
    for (int j = 0; j < 16; j++) asm volatile("" : "+v"(wselp[j]));
    #pragma unroll
    for (int j = 0; j < 16; j++) asm volatile("" : "+v"(wout2[j]));

    // ---- biases ----
    float bias_r = 0.f, bias_z = 0.f, bias_in = 0.f, bias_hn = 0.f, bsel_d = 0.f, bout_o = 0.f;
    if (tid < 128) {
        int gr = role * 128 + d;
        bias_r  = bih[gr]       + bhh[gr];
        bias_z  = bih[256 + gr] + bhh[256 + gr];
        bias_in = bih[512 + gr];
        bias_hn = bhh[512 + gr];
        bsel_d  = bsel[d];
    }
    if (tid < 64) bout_o = bout[role * 64 + tid];

    // ---- init: h=0, wx=x[:,0,:], selw[0]=1 ----
    if (tid < 128) {
        h2u[tid] = 0u;
        float x0 = x[(size_t)row * Tt * Ff + tid];
        float xp = __shfl_xor(x0, 1, 64);
        if (!(tid & 1)) {
            U32H2 v; v.h = (half2_t){ (_Float16)x0, (_Float16)xp };
            wxu[tid >> 1] = v.u;
        }
        if (role == 0) selw[(size_t)row * Ff + tid] = 1.0f;
    }
    __syncthreads();

    unsigned* flags = wsu + P_FLAG;
    unsigned* hx    = wsu + P_HX;
    unsigned* pflag = &flags[row * 2 + (role ^ 1)];

    float h_old = 0.f, ssum = 0.f;
    size_t xbase  = ((size_t)row * Tt + 1) * Ff + d;
    size_t nzbase = (size_t)row * Ff + d;
    size_t swbase = ((size_t)Bb + row) * Ff + d;
    size_t obase  = (size_t)row * Oo + role * 64 + orow;   // tid<64

    const uint4* h4 = (const uint4*)h2u;
    const uint4* w4 = (const uint4*)wxu;

    for (int t = 0; t < Tt; ++t) {
        const unsigned mbMy = ((unsigned)(t & 1) * 256u + (unsigned)(row * 2 + role)) * HXS;
        const unsigned mbP  = ((unsigned)(t & 1) * 256u + (unsigned)(row * 2 + (role ^ 1))) * HXS;

        // prefetch inputs (consumed in E; latency hidden under PH1)
        float xv = 0.f, nzv = 0.f;
        if (tid < 128 && t < Tt - 1) { xv = x[xbase]; nzv = noise[nzbase]; }

        // ---- PH1: gate partials over full h(t-1) + gi over wx(t) ----
        float a_r = 0.f, a_z = 0.f, a_in = 0.f, a_hn = 0.f;
        #pragma unroll
        for (int pp = 0; pp < 8; ++pp) {
            uint4 hv = h4[8 * q + pp];
            unsigned hh[4] = { hv.x, hv.y, hv.z, hv.w };
            #pragma unroll
            for (int i = 0; i < 4; i++) {
                a_r  = dot2f(whh2[pp * 4 + i],      hh[i], a_r);
                a_z  = dot2f(whh2[32 + pp * 4 + i], hh[i], a_z);
                a_hn = dot2f(whh2[64 + pp * 4 + i], hh[i], a_hn);
            }
        }
        #pragma unroll
        for (int pp = 0; pp < 4; ++pp) {
            uint4 wv = w4[4 * q + pp];
            unsigned ww[4] = { wv.x, wv.y, wv.z, wv.w };
            #pragma unroll
            for (int i = 0; i < 4; i++) {
                a_r  = dot2f(wih2[pp * 4 + i],      ww[i], a_r);
                a_z  = dot2f(wih2[16 + pp * 4 + i], ww[i], a_z);
                a_in = dot2f(wih2[32 + pp * 4 + i], ww[i], a_in);
            }
        }
        red[tid * 5 + 0] = a_r; red[tid * 5 + 1] = a_z;
        red[tid * 5 + 2] = a_in; red[tid * 5 + 3] = a_hn;
        __syncthreads();                               // B1

        // ---- PH2: finalize own h-half; LDS + mailbox (RELAXED: no fences) ----
        if (tid < 128) {
            float rr = bias_r, zz = bias_z, ii = bias_in, hh = bias_hn;
            #pragma unroll
            for (int qq = 0; qq < 4; qq++) {
                int b0 = (qq * 128 + d) * 5;
                rr += red[b0]; zz += red[b0 + 1]; ii += red[b0 + 2]; hh += red[b0 + 3];
            }
            float r = 1.f / (1.f + expf(-rr));
            float z = 1.f / (1.f + expf(-zz));
            float n = tanhf(ii + r * hh);
            float hn2 = (1.f - z) * n + z * h_old;
            h_old = hn2;
            float hp = __shfl_xor(hn2, 1, 64);
            if (!(d & 1)) {
                U32H2 v; v.h = (half2_t){ (_Float16)hn2, (_Float16)hp };
                h2u[role * 64 + (d >> 1)] = v.u;
                __hip_atomic_store(&hx[mbMy + (d >> 1)], v.u,
                                   __ATOMIC_RELAXED, __HIP_MEMORY_SCOPE_AGENT);
            }
        }
        __syncthreads();        // B2: barrier's vmcnt(0) drain = mailbox MALL-visible

        // flag AFTER the drain barrier -> ordered after data; store precedes the
        // same-wave spin in program order (no divergent store/spin deadlock).
        if (tid == 0)
            __hip_atomic_store(&flags[row * 2 + role], (unsigned)(t + 1),
                               __ATOMIC_RELAXED, __HIP_MEMORY_SCOPE_AGENT);

        // ---- PH3: sel/out partials over OWN half (message in flight) ----
        float p_sel = 0.f, p_out = 0.f;
        #pragma unroll
        for (int mm = 0; mm < 4; ++mm) {
            uint4 hv = h4[role * 16 + q * 4 + mm];
            unsigned hh2[4] = { hv.x, hv.y, hv.z, hv.w };
            #pragma unroll
            for (int i = 0; i < 4; i++) p_sel = dot2f(wselo[mm * 4 + i], hh2[i], p_sel);
        }
        if ((oct >> 2) == role) {
            #pragma unroll
            for (int mm = 0; mm < 4; ++mm) {
                uint4 hv = h4[oct * 4 + mm];
                unsigned hh2[4] = { hv.x, hv.y, hv.z, hv.w };
                #pragma unroll
                for (int i = 0; i < 4; i++) p_out = dot2f(wout2[mm * 4 + i], hh2[i], p_out);
            }
        }

        // ---- PH4: poll partner (relaxed; atomics bypass L1/L2 -> no acquire) ----
        if (tid < 64) {
            while (__hip_atomic_load(pflag, __ATOMIC_RELAXED, __HIP_MEMORY_SCOPE_AGENT)
                   < (unsigned)(t + 1))
                __builtin_amdgcn_s_sleep(1);
            unsigned pv = __hip_atomic_load(&hx[mbP + tid],
                                            __ATOMIC_RELAXED, __HIP_MEMORY_SCOPE_AGENT);
            h2u[(role ^ 1) * 64 + tid] = pv;
        }
        __syncthreads();                               // B3

        // ---- PH5: partner-half partials ----
        #pragma unroll
        for (int mm = 0; mm < 4; ++mm) {
            uint4 hv = h4[(role ^ 1) * 16 + q * 4 + mm];
            unsigned hh2[4] = { hv.x, hv.y, hv.z, hv.w };
            #pragma unroll
            for (int i = 0; i < 4; i++) p_sel = dot2f(wselp[mm * 4 + i], hh2[i], p_sel);
        }
        if ((oct >> 2) != role) {
            #pragma unroll
            for (int mm = 0; mm < 4; ++mm) {
                uint4 hv = h4[oct * 4 + mm];
                unsigned hh2[4] = { hv.x, hv.y, hv.z, hv.w };
                #pragma unroll
                for (int i = 0; i < 4; i++) p_out = dot2f(wout2[mm * 4 + i], hh2[i], p_out);
            }
        }
        red[tid * 5 + 0] = p_sel; red[tid * 5 + 1] = p_out;
        __syncthreads();                               // B4

        // ---- PH6: outputs, w, wx ----
        if (tid < 64) {
            float acc = bout_o;
            #pragma unroll
            for (int j = 0; j < 8; j++) acc += red[(j * 64 + tid) * 5 + 1];
            outputs[obase] = acc;
        }
        if (tid < 128 && t < Tt - 1) {
            float lg = bsel_d;
            #pragma unroll
            for (int qq = 0; qq < 4; qq++) lg += red[(qq * 128 + d) * 5 + 0];
            float arg = (lg + logf(nzv + 1e-20f) - logf(1.f - nzv + 1e-20f)) * 20.0f;
            float w = 1.f / (1.f + expf(-arg));
            if (role == 0) { selw[swbase] = w; ssum += w; }
            float wxv = w * xv;
            float wp = __shfl_xor(wxv, 1, 64);
            if (!(d & 1)) {
                U32H2 v; v.h = (half2_t){ (_Float16)wxv, (_Float16)wp };
                wxu[d >> 1] = v.u;
            }
        }
        __syncthreads();                               // B5

        obase += (size_t)Bb * Oo; nzbase += (size_t)Bb * Ff;
        swbase += (size_t)Bb * Ff; xbase += Ff;
    }

    // ---- per-row selection-sum partial (role 0 only) ----
    if (role == 0) {
        red[tid] = (tid < 128) ? ssum : 0.f;
        __syncthreads();
        for (int s = 256; s > 0; s >>= 1) {
            if (tid < s) red[tid] += red[tid + s];
            __syncthreads();
        }
        if (tid == 0) partials[row] = red[0];
    }
}

__global__ void finalize_kernel(const float* __restrict__ partials, float* __restrict__ out_scalar) {
    __shared__ float red[128];
    int t = threadIdx.x;
    red[t] = partials[t];
    __syncthreads();
    for (int s = 64; s > 0; s >>= 1) {
        if (t < s) red[t] += red[t + s];
        __syncthreads();
    }
    if (t == 0) out_scalar[0] = red[0];
}

extern "C" void kernel_launch(void* const* d_in, const int* in_sizes, int n_in,
                              void* d_out, int out_size, void* d_ws, size_t ws_size,
                              hipStream_t stream) {
    const float* x     = (const float*)d_in[0];
    const float* noise = (const float*)d_in[1];
    const float* w_ih  = (const float*)d_in[2];
    const float* w_hh  = (const float*)d_in[3];
    const float* b_ih  = (const float*)d_in[4];
    const float* b_hh  = (const float*)d_in[5];
    const float* W_out = (const float*)d_in[6];
    const float* b_out = (const float*)d_in[7];
    const float* W_sel = (const float*)d_in[8];
    const float* b_sel = (const float*)d_in[9];

    unsigned* wsu = (unsigned*)d_ws;
    float* out = (float*)d_out;
    float* outputs = out;                               // [T,B,O]
    float* nsel    = out + (size_t)Tt * Bb * Oo;        // scalar
    float* selw    = nsel + 1;                          // [T,B,F]
    float* partials = (float*)(wsu + P_PART);

    pack_kernel<<<(2 * NW * 512 + 255) / 256, 256, 0, stream>>>(w_ih, w_hh, W_sel, W_out, wsu);
    zero_flags<<<1, 256, 0, stream>>>(wsu + P_FLAG);
    gru_kernel<<<256, 512, 0, stream>>>(x, noise, b_ih, b_hh, b_out, b_sel,
                                        wsu, outputs, selw, partials);
    finalize_kernel<<<1, 128, 0, stream>>>(partials, nsel);
}